// Round 3
// baseline (6435.499 us; speedup 1.0000x reference)
//
#include <hip/hip_runtime.h>
#include <cstdint>
#include <cstddef>

#define TLEN 512
#define HD   1024

typedef short bf16x8 __attribute__((ext_vector_type(8)));
typedef float f32x4  __attribute__((ext_vector_type(4)));

#define MFMA(a, b, c) __builtin_amdgcn_mfma_f32_16x16x32_bf16((a), (b), (c), 0, 0, 0)

static __device__ __forceinline__ unsigned short f2bf(float v) {
    unsigned u = __float_as_uint(v);
    u += 0x7fffu + ((u >> 16) & 1u);          // round-to-nearest-even
    return (unsigned short)(u >> 16);
}
static __device__ __forceinline__ float bf2f(unsigned short s) {
    return __uint_as_float((unsigned)s << 16);
}

// Write-through store (past L2, to coherent L3). Drained by explicit vmcnt.
static __device__ __forceinline__ void st_bypass_u16(unsigned short* p, unsigned short v) {
    unsigned vv = v;
    asm volatile("global_store_short %0, %1, off sc0 sc1" :: "v"(p), "v"(vv) : "memory");
}
static __device__ __forceinline__ void st_bypass_u32(unsigned* p, unsigned v) {
    asm volatile("global_store_dword %0, %1, off sc0 sc1" :: "v"(p), "v"(v) : "memory");
}

// ws: arrival slots (256 x u32, one per block, monotonic step counter),
//     then at +4096: h buffers (ushort): hhi0[32K] hlo0[32K] hhi1[32K] hlo1[32K]
__global__ __launch_bounds__(512, 2)
void lstm_persist(const float* __restrict__ x,
                  const float* __restrict__ W,
                  const float* __restrict__ bias,
                  float* __restrict__ out,
                  unsigned* __restrict__ slots,
                  unsigned short* __restrict__ hbase)
{
    const int tid  = threadIdx.x;
    const int cb   = blockIdx.x;        // owns h-cols [cb*4, cb*4+4)
    const int wv   = tid >> 6;          // wave 0..7: K-slice of 128 (x) + 128 (h)
    const int lane = tid & 63;
    const int mn   = lane & 15;         // A: m (batch) / B: n (z-col)
    const int q    = lane >> 4;         // k = q*8 + j within a K-32 tile

    __shared__ f32x4 red[8][2][64];     // 16 KB partials
    __shared__ float zsh[32][17];
    __shared__ float cls[32][4];        // persistent cell state

    // ---- one-time: persistent W fragments (hi/lo bf16 split), register-resident ----
    const int zc  = (mn >> 2) * 1024 + cb * 4 + (mn & 3);
    const int kx0 = wv * 128;

    bf16x8 wxh[4], wxl[4], whh[4], whl[4];
    #pragma unroll
    for (int kk = 0; kk < 4; ++kk) {
        #pragma unroll
        for (int j = 0; j < 8; ++j) {
            const int r = kx0 + kk * 32 + q * 8 + j;
            float v = W[(size_t)r * 4096 + zc];
            unsigned short h = f2bf(v);
            wxh[kk][j] = (short)h;
            wxl[kk][j] = (short)f2bf(v - bf2f(h));
            float v2 = W[(size_t)(1024 + r) * 4096 + zc];
            unsigned short h2 = f2bf(v2);
            whh[kk][j] = (short)h2;
            whl[kk][j] = (short)f2bf(v2 - bf2f(h2));
        }
    }

    float bi = 0.f, bj = 0.f, bff = 0.f, bo = 0.f;
    if (tid < 128) {
        int b = tid >> 2, hc = tid & 3;
        int c0 = cb * 4 + hc;
        bi  = bias[c0];
        bj  = bias[1024 + c0];
        bff = bias[2048 + c0];
        bo  = bias[3072 + c0];
        cls[b][hc] = 0.f;
    }
    __syncthreads();

    f32x4 acc0 = {0.f, 0.f, 0.f, 0.f};
    f32x4 acc1 = {0.f, 0.f, 0.f, 0.f};

    auto do_xpart = [&](int tt) {
        const size_t b0 = ((size_t)mn * TLEN + tt) * HD + kx0 + q * 8;
        const size_t b1 = ((size_t)(mn + 16) * TLEN + tt) * HD + kx0 + q * 8;
        #pragma unroll
        for (int kk = 0; kk < 4; ++kk) {
            const float* p0 = x + b0 + kk * 32;
            const float* p1 = x + b1 + kk * 32;
            f32x4 a0 = *(const f32x4*)(p0);
            f32x4 a1 = *(const f32x4*)(p0 + 4);
            f32x4 c0 = *(const f32x4*)(p1);
            f32x4 c1 = *(const f32x4*)(p1 + 4);
            bf16x8 xh0, xl0, xh1, xl1;
            #pragma unroll
            for (int j = 0; j < 4; ++j) {
                float vv; unsigned short h;
                vv = a0[j]; h = f2bf(vv); xh0[j]     = (short)h; xl0[j]     = (short)f2bf(vv - bf2f(h));
                vv = a1[j]; h = f2bf(vv); xh0[4 + j] = (short)h; xl0[4 + j] = (short)f2bf(vv - bf2f(h));
                vv = c0[j]; h = f2bf(vv); xh1[j]     = (short)h; xl1[j]     = (short)f2bf(vv - bf2f(h));
                vv = c1[j]; h = f2bf(vv); xh1[4 + j] = (short)h; xl1[4 + j] = (short)f2bf(vv - bf2f(h));
            }
            acc0 = MFMA(xh0, wxh[kk], acc0);
            acc0 = MFMA(xl0, wxh[kk], acc0);
            acc0 = MFMA(xh0, wxl[kk], acc0);
            acc1 = MFMA(xh1, wxh[kk], acc1);
            acc1 = MFMA(xl1, wxh[kk], acc1);
            acc1 = MFMA(xh1, wxl[kk], acc1);
        }
    };

    // h reads are now PLAIN CACHED loads (L1+L2). Cross-XCD freshness is
    // provided by the per-step agent-acquire fence (buffer_inv sc1) below:
    // every line present in L2 at read time was filled after global publish.
    auto do_hpart = [&](const unsigned short* Hh, const unsigned short* Hl) {
        const int off0 = mn * HD + kx0 + q * 8;
        const int off1 = off0 + 16 * HD;
        bf16x8 ah0[4], al0[4], ah1[4], al1[4];
        #pragma unroll
        for (int kk = 0; kk < 4; ++kk) {
            ah0[kk] = *(const bf16x8*)(Hh + off0 + kk * 32);
            al0[kk] = *(const bf16x8*)(Hl + off0 + kk * 32);
            ah1[kk] = *(const bf16x8*)(Hh + off1 + kk * 32);
            al1[kk] = *(const bf16x8*)(Hl + off1 + kk * 32);
        }
        #pragma unroll
        for (int kk = 0; kk < 4; ++kk) {
            acc0 = MFMA(ah0[kk], whh[kk], acc0);
            acc0 = MFMA(al0[kk], whh[kk], acc0);
            acc0 = MFMA(ah0[kk], whl[kk], acc0);
            acc1 = MFMA(ah1[kk], whh[kk], acc1);
            acc1 = MFMA(al1[kk], whh[kk], acc1);
            acc1 = MFMA(ah1[kk], whl[kk], acc1);
        }
    };

    unsigned short* hhi0 = hbase;
    unsigned short* hlo0 = hbase + 32768;
    unsigned short* hhi1 = hbase + 65536;
    unsigned short* hlo1 = hbase + 98304;

    do_xpart(TLEN - 1);   // prefold x-part of step 0

    for (int t = 0; t < TLEN; ++t) {
        const unsigned short* Hh = (t & 1) ? hhi1 : hhi0;
        const unsigned short* Hl = (t & 1) ? hlo1 : hlo0;
        unsigned short* Ph = (t & 1) ? hhi0 : hhi1;
        unsigned short* Pl = (t & 1) ? hlo0 : hlo1;

        do_hpart(Hh, Hl);

        red[wv][0][lane] = acc0;
        red[wv][1][lane] = acc1;
        __syncthreads();
        if (tid < 128) {
            int tile = tid >> 6, l = tid & 63;
            f32x4 s = red[0][tile][l];
            #pragma unroll
            for (int w = 1; w < 8; ++w) s += red[w][tile][l];
            int nn = l & 15, qq = l >> 4;
            int m0 = tile * 16 + qq * 4;
            zsh[m0 + 0][nn] = s[0];
            zsh[m0 + 1][nn] = s[1];
            zsh[m0 + 2][nn] = s[2];
            zsh[m0 + 3][nn] = s[3];
        }
        __syncthreads();
        if (tid < 128) {
            int b = tid >> 2, hc = tid & 3;
            float zi = zsh[b][hc]      + bi;
            float zj = zsh[b][4 + hc]  + bj;
            float zf = zsh[b][8 + hc]  + bff;
            float zo = zsh[b][12 + hc] + bo;
            float co = cls[b][hc];
            float ig = 1.f / (1.f + expf(-zi));
            float fg = 1.f / (1.f + expf(-(zf + 1.0f)));   // forget bias = 1.0
            float og = 1.f / (1.f + expf(-zo));
            float jt = tanhf(zj);
            float cn = fg * co + ig * jt;
            float hn = og * tanhf(cn);
            cls[b][hc] = cn;
            unsigned short hh = f2bf(hn);
            unsigned short hl = f2bf(hn - bf2f(hh));
            int wi = b * HD + cb * 4 + hc;
            // order: h-hi, h-lo, out; vmcnt(1) drains the two h publishes
            // but leaves the (never-read) HBM out-store in flight.
            st_bypass_u16(Ph + wi, hh);
            st_bypass_u16(Pl + wi, hl);
            __builtin_nontemporal_store(cn, &out[((size_t)b * TLEN + t) * HD + cb * 4 + hc]);
            asm volatile("s_waitcnt vmcnt(1)" ::: "memory");
        }
        acc0 = (f32x4){0.f, 0.f, 0.f, 0.f};
        acc1 = (f32x4){0.f, 0.f, 0.f, 0.f};
        __syncthreads();   // all waves' h publishes are now drained to L3

        if (t + 1 < TLEN) {
            // store-based arrival: one monotonic 4B slot per block (no RMW).
            if (tid == 0) st_bypass_u32(&slots[cb], (unsigned)(t + 1));
            // overlap arrival propagation with next step's x-part (h-independent;
            // x values are consumed into accumulators BEFORE the invalidate below,
            // so the fence costs no x re-reads).
            do_xpart(TLEN - 2 - t);
            // direct poll: waves 0..3 each watch 64 slots (1 dword/lane,
            // 4 coalesced lines/wave); no central release word.
            if (wv < 4) {
                const unsigned tgt = (unsigned)(t + 1);
                const unsigned* sp = &slots[(wv << 6) + lane];
                while (__hip_atomic_load(sp, __ATOMIC_RELAXED,
                           __HIP_MEMORY_SCOPE_AGENT) < tgt) {
                    __builtin_amdgcn_s_sleep(1);
                }
            }
            __syncthreads();
            // One agent-acquire fence per block: s_waitcnt + buffer_inv sc1
            // invalidates this CU's L1 + this XCD's L2 stale lines, so the
            // plain h loads above re-fetch fresh data from L3 (filled there
            // by the sc0 sc1 write-through publishes, which completed before
            // any arrival store). One wave per block keeps inv traffic at
            // 2/CU/step instead of 16/CU/step.
            if (tid == 0) __builtin_amdgcn_fence(__ATOMIC_ACQUIRE, "agent");
            __syncthreads();
        }
    }
}

extern "C" void kernel_launch(void* const* d_in, const int* in_sizes, int n_in,
                              void* d_out, int out_size, void* d_ws, size_t ws_size,
                              hipStream_t stream)
{
    (void)in_sizes; (void)n_in; (void)out_size; (void)ws_size;
    const float* x    = (const float*)d_in[0];
    // d_in[1] = sl (unused by reference)
    const float* W    = (const float*)d_in[2];
    const float* bias = (const float*)d_in[3];
    float* out = (float*)d_out;

    unsigned* slots = (unsigned*)d_ws;
    unsigned short* hbase = (unsigned short*)((char*)d_ws + 4096);

    // zero arrival slots + h double-buffers; stream-ordered memset is
    // cache-coherent w.r.t. the following kernel (kernel-boundary flush)
    hipMemsetAsync(d_ws, 0, 4096 + 262144, stream);

    lstm_persist<<<256, 512, 0, stream>>>(x, W, bias, out, slots, hbase);
}

// Round 4
// 3378.524 us; speedup vs baseline: 1.9048x; 1.9048x over previous
//
#include <hip/hip_runtime.h>
#include <cstdint>
#include <cstddef>

#define TLEN 512
#define HD   1024

typedef short bf16x8 __attribute__((ext_vector_type(8)));
typedef float f32x4  __attribute__((ext_vector_type(4)));

#define MFMA(a, b, c) __builtin_amdgcn_mfma_f32_16x16x32_bf16((a), (b), (c), 0, 0, 0)

static __device__ __forceinline__ unsigned short f2bf(float v) {
    unsigned u = __float_as_uint(v);
    u += 0x7fffu + ((u >> 16) & 1u);          // round-to-nearest-even
    return (unsigned short)(u >> 16);
}
static __device__ __forceinline__ float bf2f(unsigned short s) {
    return __uint_as_float((unsigned)s << 16);
}

// Coherent (L2-bypassing) 16B h-load as ONE dwordx4 with sc0 sc1.
// NO implicit wait — caller must s_waitcnt vmcnt(0) (+ sched_barrier) before use.
static __device__ __forceinline__ bf16x8 ld_h16a(const unsigned short* p) {
    bf16x8 r;
    asm volatile("global_load_dwordx4 %0, %1, off sc0 sc1"
                 : "=&v"(r) : "v"(p) : "memory");
    return r;
}

// Write-through store (past L2, to coherent L3). Drained by explicit vmcnt.
static __device__ __forceinline__ void st_bypass_u16(unsigned short* p, unsigned short v) {
    unsigned vv = v;
    asm volatile("global_store_short %0, %1, off sc0 sc1" :: "v"(p), "v"(vv) : "memory");
}
static __device__ __forceinline__ void st_bypass_u32(unsigned* p, unsigned v) {
    asm volatile("global_store_dword %0, %1, off sc0 sc1" :: "v"(p), "v"(v) : "memory");
}

// 256 blocks = 2 batch-groups x 128 col-groups.
// Block (bg, hcb): owns batches [bg*16, bg*16+16) x h-cols [hcb*8, hcb*8+8).
// Halves the per-step broadcast volume (h: 32->16 MB, x: 32->16 MB chip-wide)
// vs the 32-batch x 4-col layout, at the cost of 2x W fragments (~128 VGPR,
// free at 1 block/CU).
// ws: arrival slots (256 x u32), +4096: hhi0[32K] hlo0[32K] hhi1[32K] hlo1[32K]
__global__ __launch_bounds__(512, 2)
void lstm_persist(const float* __restrict__ x,
                  const float* __restrict__ W,
                  const float* __restrict__ bias,
                  float* __restrict__ out,
                  unsigned* __restrict__ slots,
                  unsigned short* __restrict__ hbase)
{
    const int tid  = threadIdx.x;
    const int cb   = blockIdx.x;
    const int bg   = cb >> 7;           // batch group: rows [bg*16, bg*16+16)
    const int hcb  = cb & 127;          // h-cols [hcb*8, hcb*8+8)
    const int wv   = tid >> 6;          // wave 0..7: K-slice of 128 (x) + 128 (h)
    const int lane = tid & 63;
    const int mn   = lane & 15;         // A: m (batch) / B: n (z-col within frag)
    const int q    = lane >> 4;         // k = q*8 + j within a K-32 tile

    __shared__ f32x4 red[8][2][64];     // 16 KB partials
    __shared__ float zsh[16][33];
    __shared__ float cls[16][8];        // persistent cell state

    // ---- one-time: persistent W fragments (hi/lo bf16 split), register-resident.
    // frag 0: z-cols = gate(0,1)*1024 + hcb*8 + col;  frag 1: gates (2,3).
    const int zc0 = ((mn >> 3)    ) * 1024 + hcb * 8 + (mn & 7);
    const int zc1 = ((mn >> 3) + 2) * 1024 + hcb * 8 + (mn & 7);
    const int kx0 = wv * 128;

    bf16x8 wxh[4][2], wxl[4][2], whh[4][2], whl[4][2];
    #pragma unroll
    for (int kk = 0; kk < 4; ++kk) {
        #pragma unroll
        for (int j = 0; j < 8; ++j) {
            const int r = kx0 + kk * 32 + q * 8 + j;
            float v0 = W[(size_t)r * 4096 + zc0];
            unsigned short h0 = f2bf(v0);
            wxh[kk][0][j] = (short)h0;
            wxl[kk][0][j] = (short)f2bf(v0 - bf2f(h0));
            float v1 = W[(size_t)r * 4096 + zc1];
            unsigned short h1 = f2bf(v1);
            wxh[kk][1][j] = (short)h1;
            wxl[kk][1][j] = (short)f2bf(v1 - bf2f(h1));
            float u0 = W[(size_t)(1024 + r) * 4096 + zc0];
            unsigned short g0 = f2bf(u0);
            whh[kk][0][j] = (short)g0;
            whl[kk][0][j] = (short)f2bf(u0 - bf2f(g0));
            float u1 = W[(size_t)(1024 + r) * 4096 + zc1];
            unsigned short g1 = f2bf(u1);
            whh[kk][1][j] = (short)g1;
            whl[kk][1][j] = (short)f2bf(u1 - bf2f(g1));
        }
    }

    float bi = 0.f, bj = 0.f, bff = 0.f, bo = 0.f;
    if (tid < 128) {
        int b = tid >> 3, hc = tid & 7;
        int c0 = hcb * 8 + hc;
        bi  = bias[c0];
        bj  = bias[1024 + c0];
        bff = bias[2048 + c0];
        bo  = bias[3072 + c0];
        cls[b][hc] = 0.f;
    }
    __syncthreads();

    f32x4 acc0 = {0.f, 0.f, 0.f, 0.f};
    f32x4 acc1 = {0.f, 0.f, 0.f, 0.f};

    auto do_xpart = [&](int tt) {
        const size_t b0 = ((size_t)(bg * 16 + mn) * TLEN + tt) * HD + kx0 + q * 8;
        #pragma unroll
        for (int kk = 0; kk < 4; ++kk) {
            const float* p0 = x + b0 + kk * 32;
            f32x4 a0 = *(const f32x4*)(p0);
            f32x4 a1 = *(const f32x4*)(p0 + 4);
            bf16x8 xh, xl;
            #pragma unroll
            for (int j = 0; j < 4; ++j) {
                float vv; unsigned short h;
                vv = a0[j]; h = f2bf(vv); xh[j]     = (short)h; xl[j]     = (short)f2bf(vv - bf2f(h));
                vv = a1[j]; h = f2bf(vv); xh[4 + j] = (short)h; xl[4 + j] = (short)f2bf(vv - bf2f(h));
            }
            acc0 = MFMA(xh, wxh[kk][0], acc0);
            acc0 = MFMA(xl, wxh[kk][0], acc0);
            acc0 = MFMA(xh, wxl[kk][0], acc0);
            acc1 = MFMA(xh, wxh[kk][1], acc1);
            acc1 = MFMA(xl, wxh[kk][1], acc1);
            acc1 = MFMA(xh, wxl[kk][1], acc1);
        }
    };

    auto do_hpart = [&](const unsigned short* Hh, const unsigned short* Hl) {
        const int off = (bg * 16 + mn) * HD + kx0 + q * 8;
        bf16x8 ah[4], al[4];
        // issue all 8 x 16B L2-bypass loads back-to-back (fully pipelined),
        #pragma unroll
        for (int kk = 0; kk < 4; ++kk) {
            ah[kk] = ld_h16a(Hh + off + kk * 32);
            al[kk] = ld_h16a(Hl + off + kk * 32);
        }
        // ...then ONE drain; sched_barrier keeps MFMAs below the waitcnt (rule #18)
        asm volatile("s_waitcnt vmcnt(0)" ::: "memory");
        __builtin_amdgcn_sched_barrier(0);
        #pragma unroll
        for (int kk = 0; kk < 4; ++kk) {
            acc0 = MFMA(ah[kk], whh[kk][0], acc0);
            acc0 = MFMA(al[kk], whh[kk][0], acc0);
            acc0 = MFMA(ah[kk], whl[kk][0], acc0);
            acc1 = MFMA(ah[kk], whh[kk][1], acc1);
            acc1 = MFMA(al[kk], whh[kk][1], acc1);
            acc1 = MFMA(ah[kk], whl[kk][1], acc1);
        }
    };

    unsigned short* hhi0 = hbase;
    unsigned short* hlo0 = hbase + 32768;
    unsigned short* hhi1 = hbase + 65536;
    unsigned short* hlo1 = hbase + 98304;

    do_xpart(TLEN - 1);   // prefold x-part of step 0

    for (int t = 0; t < TLEN; ++t) {
        const unsigned short* Hh = (t & 1) ? hhi1 : hhi0;
        const unsigned short* Hl = (t & 1) ? hlo1 : hlo0;
        unsigned short* Ph = (t & 1) ? hhi0 : hhi1;
        unsigned short* Pl = (t & 1) ? hlo0 : hlo1;

        do_hpart(Hh, Hl);

        red[wv][0][lane] = acc0;
        red[wv][1][lane] = acc1;
        __syncthreads();
        if (tid < 128) {
            int frag = tid >> 6, l = tid & 63;
            f32x4 s = red[0][frag][l];
            #pragma unroll
            for (int w = 1; w < 8; ++w) s += red[w][frag][l];
            int nn = l & 15, qq = l >> 4;
            int m0 = qq * 4;
            zsh[m0 + 0][frag * 16 + nn] = s[0];
            zsh[m0 + 1][frag * 16 + nn] = s[1];
            zsh[m0 + 2][frag * 16 + nn] = s[2];
            zsh[m0 + 3][frag * 16 + nn] = s[3];
        }
        __syncthreads();
        if (tid < 128) {
            int b = tid >> 3, hc = tid & 7;
            float zi = zsh[b][hc]      + bi;
            float zj = zsh[b][8 + hc]  + bj;
            float zf = zsh[b][16 + hc] + bff;
            float zo = zsh[b][24 + hc] + bo;
            float co = cls[b][hc];
            float ig = 1.f / (1.f + expf(-zi));
            float fg = 1.f / (1.f + expf(-(zf + 1.0f)));   // forget bias = 1.0
            float og = 1.f / (1.f + expf(-zo));
            float jt = tanhf(zj);
            float cn = fg * co + ig * jt;
            float hn = og * tanhf(cn);
            cls[b][hc] = cn;
            unsigned short hh = f2bf(hn);
            unsigned short hl = f2bf(hn - bf2f(hh));
            int wi = (bg * 16 + b) * HD + hcb * 8 + hc;
            // order: h-hi, h-lo, out; vmcnt(1) drains the two h publishes
            // but leaves the (never-read) HBM out-store in flight.
            st_bypass_u16(Ph + wi, hh);
            st_bypass_u16(Pl + wi, hl);
            __builtin_nontemporal_store(cn,
                &out[((size_t)(bg * 16 + b) * TLEN + t) * HD + hcb * 8 + hc]);
            asm volatile("s_waitcnt vmcnt(1)" ::: "memory");
        }
        acc0 = (f32x4){0.f, 0.f, 0.f, 0.f};
        acc1 = (f32x4){0.f, 0.f, 0.f, 0.f};
        __syncthreads();   // all waves' h publishes are now drained to L3

        if (t + 1 < TLEN) {
            // store-based arrival: one monotonic 4B slot per block (no RMW).
            if (tid == 0) st_bypass_u32(&slots[cb], (unsigned)(t + 1));
            // overlap arrival propagation with next step's x-part (h-independent)
            do_xpart(TLEN - 2 - t);
            // direct poll: waves 0..3 each watch 64 slots (1 dword/lane,
            // 4 coalesced lines/wave); no central release word.
            if (wv < 4) {
                const unsigned tgt = (unsigned)(t + 1);
                const unsigned* sp = &slots[(wv << 6) + lane];
                while (__hip_atomic_load(sp, __ATOMIC_RELAXED,
                           __HIP_MEMORY_SCOPE_AGENT) < tgt) {
                    __builtin_amdgcn_s_sleep(1);
                }
            }
            __syncthreads();
            // NO acquire fence: h reads bypass L2 (coherent at L3);
            // x/W/bias are read-only; out is write-only; c lives in LDS.
        }
    }
}

extern "C" void kernel_launch(void* const* d_in, const int* in_sizes, int n_in,
                              void* d_out, int out_size, void* d_ws, size_t ws_size,
                              hipStream_t stream)
{
    (void)in_sizes; (void)n_in; (void)out_size; (void)ws_size;
    const float* x    = (const float*)d_in[0];
    // d_in[1] = sl (unused by reference)
    const float* W    = (const float*)d_in[2];
    const float* bias = (const float*)d_in[3];
    float* out = (float*)d_out;

    unsigned* slots = (unsigned*)d_ws;
    unsigned short* hbase = (unsigned short*)((char*)d_ws + 4096);

    // zero arrival slots + h double-buffers; stream-ordered memset is
    // cache-coherent w.r.t. the following kernel (kernel-boundary flush)
    hipMemsetAsync(d_ws, 0, 4096 + 262144, stream);

    lstm_persist<<<256, 512, 0, stream>>>(x, W, bias, out, slots, hbase);
}